// Round 1
// 1023.040 us; speedup vs baseline: 1.0985x; 1.0985x over previous
//
#include <hip/hip_runtime.h>

#define MM 1024
#define NN 4096
#define DD 128
#define HH 32
#define PP 3072
#define LL 4096   // P + M

typedef __attribute__((ext_vector_type(8))) short short8;
typedef __attribute__((ext_vector_type(4))) float f32x4;

__device__ __forceinline__ float bf2f(short b) {
  union { unsigned u; float f; } c;
  c.u = ((unsigned)(unsigned short)b) << 16;
  return c.f;
}

__device__ __forceinline__ short f2bf(float f) {
  union { float f; unsigned u; } c; c.f = f;
  unsigned r = c.u + 0x7FFFu + ((c.u >> 16) & 1u);  // RNE
  return (short)(r >> 16);
}

// split f32 -> bf16 hi + bf16 lo (x ~= hi + lo, residual ~2^-16 rel)
struct bf2 { short hi, lo; };
__device__ __forceinline__ bf2 split2(float x) {
  bf2 r;
  r.hi = f2bf(x);
  r.lo = f2bf(x - bf2f(r.hi));
  return r;
}

// 8 consecutive f32 -> 8 bf16 (plain cast)
__device__ __forceinline__ short8 cvt8(const float* __restrict__ p) {
  const f32x4 a = *(const f32x4*)p;
  const f32x4 b = *(const f32x4*)(p + 4);
  short8 r;
  r[0] = f2bf(a[0]); r[1] = f2bf(a[1]); r[2] = f2bf(a[2]); r[3] = f2bf(a[3]);
  r[4] = f2bf(b[0]); r[5] = f2bf(b[1]); r[6] = f2bf(b[2]); r[7] = f2bf(b[3]);
  return r;
}

// async global -> LDS, 16B per lane, LDS dest = wave-uniform base + lane*16
__device__ __forceinline__ void gload16(const void* g, void* l) {
  __builtin_amdgcn_global_load_lds(
      (const __attribute__((address_space(1))) void*)g,
      (__attribute__((address_space(3))) void*)l, 16, 0, 0);
}

// ---------------------------------------------------------------------------
// Split X f32 -> Xhi, Xlo bf16 (8 elems/thread).
// ---------------------------------------------------------------------------
__global__ __launch_bounds__(256) void split_x(
    const float* __restrict__ in, short* __restrict__ oh,
    short* __restrict__ ol, int n8)
{
  int i = blockIdx.x * blockDim.x + threadIdx.x;
  if (i >= n8) return;
  const float* p = in + (size_t)i * 8;
  f32x4 a = *(const f32x4*)p, b = *(const f32x4*)(p + 4);
  short8 h, l;
  #pragma unroll
  for (int j = 0; j < 4; ++j) {
    bf2 ra = split2(a[j]); h[j] = ra.hi; l[j] = ra.lo;
    bf2 rb = split2(b[j]); h[4 + j] = rb.hi; l[4 + j] = rb.lo;
  }
  *(short8*)(oh + (size_t)i * 8) = h;
  *(short8*)(ol + (size_t)i * 8) = l;
}

// ---------------------------------------------------------------------------
// Split + transpose W: f32 [K][N] -> bf16 hi/lo [N][K] (K-major).
// Block covers 64 k x 256 n; each thread transposes an 8x8 block in
// registers. Reads fully coalesced (32 lanes x 32B per k-row).
// Writes 16B/lane; lanes l and l+32 pair to contiguous 32B.
// ol == nullptr -> hi only (used for W_v).
// ---------------------------------------------------------------------------
__global__ __launch_bounds__(256) void split_w_t(
    const float* __restrict__ W, short* __restrict__ oh,
    short* __restrict__ ol)
{
  const int n0 = blockIdx.x * 256;
  const int k0 = blockIdx.y * 64;
  const int t  = threadIdx.x;
  const int k8 = k0 + ((t >> 5) << 3);   // 8-row k block
  const int n8 = n0 + ((t & 31) << 3);   // 8-col n block

  f32x4 xa[8], xb[8];
  #pragma unroll
  for (int r = 0; r < 8; ++r) {
    const float* p = W + (size_t)(k8 + r) * 4096 + n8;
    xa[r] = *(const f32x4*)p;
    xb[r] = *(const f32x4*)(p + 4);
  }
  #pragma unroll
  for (int c = 0; c < 8; ++c) {
    short8 th, tl;
    #pragma unroll
    for (int r = 0; r < 8; ++r) {
      float v = (c < 4) ? xa[r][c] : xb[r][c - 4];
      bf2 s = split2(v);
      th[r] = s.hi; tl[r] = s.lo;
    }
    size_t o = (size_t)(n8 + c) * 4096 + k8;
    *(short8*)(oh + o) = th;
    if (ol) *(short8*)(ol + o) = tl;
  }
}

// ---------------------------------------------------------------------------
// Split-precision bf16 GEMM, B^T layout (m97 structure):
//   O f32 [M][N] = Xh+Xl  @  (Wh+Wl)^T   (3 MFMA terms: hh, hl, lh)
// Tile 128x128, BK=64, 4 waves (2x2 of 64x64), mfma 16x16x32.
// All four operand tiles staged with global_load_lds width=16 into linear
// LDS [128][64]; A and B fragments are contiguous-k ds_read_b128.
// ---------------------------------------------------------------------------
__global__ __launch_bounds__(256) void gemm_split_bt(
    const short* __restrict__ Ah_g, const short* __restrict__ Al_g,
    const short* __restrict__ Bh_g, const short* __restrict__ Bl_g,
    float* __restrict__ O)
{
  const int n0 = blockIdx.x * 128;
  const int m0 = blockIdx.y * 128;
  const int t  = threadIdx.x;
  const int wave = t >> 6;
  const int lane = t & 63;
  const int ln   = lane & 15;
  const int quad = lane >> 4;
  const int q8   = quad * 8;
  const int wm = (wave >> 1) * 64;
  const int wn = (wave & 1) * 64;
  const int sr = lane >> 3;        // sub-row within 8-row staging chunk
  const int sc = (lane & 7) * 8;   // k offset within row

  __shared__ short Ash[128 * 64];
  __shared__ short Asl[128 * 64];
  __shared__ short Bsh[128 * 64];
  __shared__ short Bsl[128 * 64];

  f32x4 acc[4][4];
  #pragma unroll
  for (int mi = 0; mi < 4; ++mi)
    #pragma unroll
    for (int ni = 0; ni < 4; ++ni)
      acc[mi][ni] = (f32x4){0.f, 0.f, 0.f, 0.f};

  const size_t a_base = (size_t)(m0 + wave * 32 + sr) * 4096 + sc;
  const size_t b_base = (size_t)(n0 + wave * 32 + sr) * 4096 + sc;
  const int l_base = wave * 32 * 64;  // shorts

  for (int kt = 0; kt < 4096; kt += 64) {
    #pragma unroll
    for (int i = 0; i < 4; ++i) {
      size_t ao = a_base + kt + (size_t)(i * 8) * 4096;
      size_t bo = b_base + kt + (size_t)(i * 8) * 4096;
      int lo = l_base + i * 8 * 64;
      gload16(Ah_g + ao, Ash + lo);
      gload16(Al_g + ao, Asl + lo);
      gload16(Bh_g + bo, Bsh + lo);
      gload16(Bl_g + bo, Bsl + lo);
    }
    __syncthreads();
    #pragma unroll
    for (int kk = 0; kk < 64; kk += 32) {
      short8 ah[4], al[4], bh[4], bl[4];
      #pragma unroll
      for (int mi = 0; mi < 4; ++mi) {
        int ro = (wm + mi * 16 + ln) * 64 + kk + q8;
        ah[mi] = *(const short8*)(Ash + ro);
        al[mi] = *(const short8*)(Asl + ro);
      }
      #pragma unroll
      for (int ni = 0; ni < 4; ++ni) {
        int ro = (wn + ni * 16 + ln) * 64 + kk + q8;
        bh[ni] = *(const short8*)(Bsh + ro);
        bl[ni] = *(const short8*)(Bsl + ro);
      }
      #pragma unroll
      for (int ni = 0; ni < 4; ++ni)
        #pragma unroll
        for (int mi = 0; mi < 4; ++mi) {
          acc[mi][ni] = __builtin_amdgcn_mfma_f32_16x16x32_bf16(ah[mi], bh[ni], acc[mi][ni], 0, 0, 0);
          acc[mi][ni] = __builtin_amdgcn_mfma_f32_16x16x32_bf16(ah[mi], bl[ni], acc[mi][ni], 0, 0, 0);
          acc[mi][ni] = __builtin_amdgcn_mfma_f32_16x16x32_bf16(al[mi], bh[ni], acc[mi][ni], 0, 0, 0);
        }
    }
    __syncthreads();
  }

  #pragma unroll
  for (int mi = 0; mi < 4; ++mi)
    #pragma unroll
    for (int ni = 0; ni < 4; ++ni)
      #pragma unroll
      for (int r = 0; r < 4; ++r) {
        int row = m0 + wm + mi * 16 + quad * 4 + r;
        int col = n0 + wn + ni * 16 + ln;
        O[(size_t)row * 4096 + col] = acc[mi][ni][r];
      }
}

// ---------------------------------------------------------------------------
// Plain bf16 GEMM, B^T layout: Ov bf16 = Xh @ Wth^T. Same structure.
// ---------------------------------------------------------------------------
__global__ __launch_bounds__(256) void gemm_bf16_bt(
    const short* __restrict__ Ah_g, const short* __restrict__ Bh_g,
    short* __restrict__ Ov)
{
  const int n0 = blockIdx.x * 128;
  const int m0 = blockIdx.y * 128;
  const int t  = threadIdx.x;
  const int wave = t >> 6;
  const int lane = t & 63;
  const int ln   = lane & 15;
  const int quad = lane >> 4;
  const int q8   = quad * 8;
  const int wm = (wave >> 1) * 64;
  const int wn = (wave & 1) * 64;
  const int sr = lane >> 3;
  const int sc = (lane & 7) * 8;

  __shared__ short Ash[128 * 64];
  __shared__ short Bsh[128 * 64];

  f32x4 acc[4][4];
  #pragma unroll
  for (int mi = 0; mi < 4; ++mi)
    #pragma unroll
    for (int ni = 0; ni < 4; ++ni)
      acc[mi][ni] = (f32x4){0.f, 0.f, 0.f, 0.f};

  const size_t a_base = (size_t)(m0 + wave * 32 + sr) * 4096 + sc;
  const size_t b_base = (size_t)(n0 + wave * 32 + sr) * 4096 + sc;
  const int l_base = wave * 32 * 64;

  for (int kt = 0; kt < 4096; kt += 64) {
    #pragma unroll
    for (int i = 0; i < 4; ++i) {
      size_t ao = a_base + kt + (size_t)(i * 8) * 4096;
      size_t bo = b_base + kt + (size_t)(i * 8) * 4096;
      int lo = l_base + i * 8 * 64;
      gload16(Ah_g + ao, Ash + lo);
      gload16(Bh_g + bo, Bsh + lo);
    }
    __syncthreads();
    #pragma unroll
    for (int kk = 0; kk < 64; kk += 32) {
      short8 ah[4], bh[4];
      #pragma unroll
      for (int mi = 0; mi < 4; ++mi)
        ah[mi] = *(const short8*)(Ash + (wm + mi * 16 + ln) * 64 + kk + q8);
      #pragma unroll
      for (int ni = 0; ni < 4; ++ni)
        bh[ni] = *(const short8*)(Bsh + (wn + ni * 16 + ln) * 64 + kk + q8);
      #pragma unroll
      for (int ni = 0; ni < 4; ++ni)
        #pragma unroll
        for (int mi = 0; mi < 4; ++mi)
          acc[mi][ni] = __builtin_amdgcn_mfma_f32_16x16x32_bf16(ah[mi], bh[ni], acc[mi][ni], 0, 0, 0);
    }
    __syncthreads();
  }

  #pragma unroll
  for (int mi = 0; mi < 4; ++mi)
    #pragma unroll
    for (int ni = 0; ni < 4; ++ni)
      #pragma unroll
      for (int r = 0; r < 4; ++r) {
        int row = m0 + wm + mi * 16 + quad * 4 + r;
        int col = n0 + wn + ni * 16 + ln;
        Ov[(size_t)row * 4096 + col] = f2bf(acc[mi][ni][r]);
      }
}

// ---------------------------------------------------------------------------
// RMS-norm f32 in place per (row, head): 8 lanes/head, 16 f32/lane.
// grid (1024, 2): y==0 -> Q, y==1 -> K.
// ---------------------------------------------------------------------------
__global__ __launch_bounds__(256) void rmsnorm_f32(
    float* __restrict__ Q, float* __restrict__ K)
{
  float* __restrict__ buf = (blockIdx.y == 0) ? Q : K;
  const int m = blockIdx.x;
  const int t = threadIdx.x;
  const int head = t >> 3, li = t & 7;
  size_t base = (size_t)m * 4096 + head * 128 + li * 16;

  f32x4 a[4];
  float ss = 0.f;
  #pragma unroll
  for (int i = 0; i < 4; ++i) {
    a[i] = *(const f32x4*)(buf + base + i * 4);
    #pragma unroll
    for (int j = 0; j < 4; ++j) ss += a[i][j] * a[i][j];
  }
  #pragma unroll
  for (int d = 1; d < 8; d <<= 1) ss += __shfl_xor(ss, d, 64);
  float scale = rsqrtf(ss * (1.0f / 128.0f));
  #pragma unroll
  for (int i = 0; i < 4; ++i) {
    #pragma unroll
    for (int j = 0; j < 4; ++j) a[i][j] *= scale;
    *(f32x4*)(buf + base + i * 4) = a[i];
  }
}

// ---------------------------------------------------------------------------
// Flash attention, 64 q-rows/block, 4 waves (wave w owns q-rows 16w..16w+16
// for QK^T + softmax; owns d-subtiles {2w,2w+1} for PV).
// QK^T in 3-term bf16 split (q,k split on the fly from f32 sources).
// In-register wave-private online softmax. P round-trips LDS as bf16.
// V natural [key][d] LDS with XOR block swizzle for the u16 frag gather.
// ---------------------------------------------------------------------------
__global__ __launch_bounds__(256) void attn(
    const float* __restrict__ Qf,   // [M][4096] f32 rms-normed q
    const float* __restrict__ Kf,   // [M][4096] f32 rms-normed k
    const short* __restrict__ Vb,   // [M][4096] bf16 v
    const float* __restrict__ cK,   // [H][P][D] f32
    const float* __restrict__ cV,   // [H][P][D] f32
    float* __restrict__ Out)        // [M][4096] f32
{
  const int h  = blockIdx.y;
  const int m0 = blockIdx.x * 64;
  const int t  = threadIdx.x;
  const int w    = t >> 6;
  const int lane = t & 63;
  const int ln   = lane & 15;
  const int quad = lane >> 4;
  const int q8   = quad * 8;

  __shared__ short k_hi[64 * 136];
  __shared__ short k_lo[64 * 136];
  __shared__ short v_s[64 * 136];
  __shared__ short p_s[64 * 72];
  __shared__ float a_l[64], l_l[64];

  // q fragments from global, split in registers (A layout: m=ln, k=q8+j)
  short8 qh[4], ql[4];
  {
    int qrow = m0 + w * 16 + ln;
    #pragma unroll
    for (int dc = 0; dc < 4; ++dc) {
      const float* qp = Qf + (size_t)qrow * 4096 + h * 128 + dc * 32 + q8;
      f32x4 a = *(const f32x4*)qp, b = *(const f32x4*)(qp + 4);
      #pragma unroll
      for (int j = 0; j < 4; ++j) {
        bf2 ra = split2(a[j]); qh[dc][j] = ra.hi; ql[dc][j] = ra.lo;
        bf2 rb = split2(b[j]); qh[dc][4 + j] = rb.hi; ql[dc][4 + j] = rb.lo;
      }
    }
  }

  float m_st[4], l_st[4];
  #pragma unroll
  for (int r = 0; r < 4; ++r) { m_st[r] = -1e30f; l_st[r] = 0.f; }

  f32x4 oacc[4][2];
  #pragma unroll
  for (int ms = 0; ms < 4; ++ms)
    #pragma unroll
    for (int i = 0; i < 2; ++i)
      oacc[ms][i] = (f32x4){0.f, 0.f, 0.f, 0.f};

  for (int kb = 0; kb < LL; kb += 64) {
    // ---- stage K (split) and V (bf16) : 64 keys x 128 d
    #pragma unroll
    for (int i = 0; i < 2; ++i) {
      int kr = i * 32 + (t >> 3);
      int g  = kb + kr;
      int dc = (t & 7) * 16;
      const float* ks = (g < PP)
          ? cK + ((size_t)h * PP + g) * 128 + dc
          : Kf + (size_t)(g - PP) * 4096 + h * 128 + dc;
      f32x4 x0 = *(const f32x4*)ks,       x1 = *(const f32x4*)(ks + 4);
      f32x4 x2 = *(const f32x4*)(ks + 8), x3 = *(const f32x4*)(ks + 12);
      short8 h0, l0, h1, l1;
      #pragma unroll
      for (int j = 0; j < 4; ++j) {
        bf2 r0 = split2(x0[j]); h0[j] = r0.hi; l0[j] = r0.lo;
        bf2 r1 = split2(x1[j]); h0[4 + j] = r1.hi; l0[4 + j] = r1.lo;
        bf2 r2 = split2(x2[j]); h1[j] = r2.hi; l1[j] = r2.lo;
        bf2 r3 = split2(x3[j]); h1[4 + j] = r3.hi; l1[4 + j] = r3.lo;
      }
      *(short8*)(k_hi + kr * 136 + dc)     = h0;
      *(short8*)(k_hi + kr * 136 + dc + 8) = h1;
      *(short8*)(k_lo + kr * 136 + dc)     = l0;
      *(short8*)(k_lo + kr * 136 + dc + 8) = l1;

      short8 v0, v1;
      if (g < PP) {
        const float* vs = cV + ((size_t)h * PP + g) * 128 + dc;
        v0 = cvt8(vs); v1 = cvt8(vs + 8);
      } else {
        const short* vp = Vb + (size_t)(g - PP) * 4096 + h * 128 + dc;
        v0 = *(const short8*)vp; v1 = *(const short8*)(vp + 8);
      }
      int b0 = ((dc >> 3) + 0) ^ (kr >> 3);
      int b1 = ((dc >> 3) + 1) ^ (kr >> 3);
      *(short8*)(v_s + kr * 136 + b0 * 8) = v0;
      *(short8*)(v_s + kr * 136 + b1 * 8) = v1;
    }
    __syncthreads();

    // ---- S = q K^T (wave's 16 rows x 64 keys), 3-term split
    f32x4 sacc[4];
    #pragma unroll
    for (int ni = 0; ni < 4; ++ni) sacc[ni] = (f32x4){0.f, 0.f, 0.f, 0.f};
    #pragma unroll
    for (int ni = 0; ni < 4; ++ni) {
      #pragma unroll
      for (int dc = 0; dc < 4; ++dc) {
        int ro = (ni * 16 + ln) * 136 + dc * 32 + q8;
        short8 kh = *(const short8*)(k_hi + ro);
        short8 kl = *(const short8*)(k_lo + ro);
        sacc[ni] = __builtin_amdgcn_mfma_f32_16x16x32_bf16(qh[dc], kh, sacc[ni], 0, 0, 0);
        sacc[ni] = __builtin_amdgcn_mfma_f32_16x16x32_bf16(qh[dc], kl, sacc[ni], 0, 0, 0);
        sacc[ni] = __builtin_amdgcn_mfma_f32_16x16x32_bf16(ql[dc], kh, sacc[ni], 0, 0, 0);
      }
    }

    // ---- wave-private online softmax (rows quad*4+rr of this wave)
    float alpha[4];
    #pragma unroll
    for (int rr = 0; rr < 4; ++rr) {
      float mx = fmaxf(fmaxf(sacc[0][rr], sacc[1][rr]),
                       fmaxf(sacc[2][rr], sacc[3][rr]));
      #pragma unroll
      for (int d = 1; d < 16; d <<= 1) mx = fmaxf(mx, __shfl_xor(mx, d, 64));
      float mn = fmaxf(m_st[rr], mx);
      alpha[rr] = __expf(m_st[rr] - mn);
      float p0 = __expf(sacc[0][rr] - mn);
      float p1 = __expf(sacc[1][rr] - mn);
      float p2 = __expf(sacc[2][rr] - mn);
      float p3 = __expf(sacc[3][rr] - mn);
      float s = p0 + p1 + p2 + p3;
      #pragma unroll
      for (int d = 1; d < 16; d <<= 1) s += __shfl_xor(s, d, 64);
      l_st[rr] = l_st[rr] * alpha[rr] + s;
      m_st[rr] = mn;
      int prow = (w * 16 + quad * 4 + rr) * 72;
      p_s[prow + 0 * 16 + ln] = f2bf(p0);
      p_s[prow + 1 * 16 + ln] = f2bf(p1);
      p_s[prow + 2 * 16 + ln] = f2bf(p2);
      p_s[prow + 3 * 16 + ln] = f2bf(p3);
    }
    if (ln == 0) {
      #pragma unroll
      for (int rr = 0; rr < 4; ++rr) a_l[w * 16 + quad * 4 + rr] = alpha[rr];
    }
    __syncthreads();

    // ---- rescale O, then O += P V (wave owns d-subtiles 2w, 2w+1)
    #pragma unroll
    for (int ms = 0; ms < 4; ++ms) {
      f32x4 av = *(const f32x4*)(a_l + ms * 16 + quad * 4);
      #pragma unroll
      for (int i = 0; i < 2; ++i)
        #pragma unroll
        for (int r = 0; r < 4; ++r) oacc[ms][i][r] *= av[r];
    }
    #pragma unroll
    for (int kk = 0; kk < 64; kk += 32) {
      short8 vf[2];
      #pragma unroll
      for (int i = 0; i < 2; ++i) {
        int cbb = (w * 2 + i) * 2 + (ln >> 3);
        #pragma unroll
        for (int j = 0; j < 8; ++j) {
          int k = kk + q8 + j;
          vf[i][j] = v_s[k * 136 + ((cbb ^ (k >> 3)) << 3) + (ln & 7)];
        }
      }
      #pragma unroll
      for (int ms = 0; ms < 4; ++ms) {
        short8 pf = *(const short8*)(p_s + (ms * 16 + ln) * 72 + kk + q8);
        #pragma unroll
        for (int i = 0; i < 2; ++i)
          oacc[ms][i] = __builtin_amdgcn_mfma_f32_16x16x32_bf16(pf, vf[i], oacc[ms][i], 0, 0, 0);
      }
    }
    __syncthreads();
  }

  if (ln == 0) {
    #pragma unroll
    for (int rr = 0; rr < 4; ++rr) l_l[w * 16 + quad * 4 + rr] = l_st[rr];
  }
  __syncthreads();

  #pragma unroll
  for (int ms = 0; ms < 4; ++ms) {
    f32x4 lv = *(const f32x4*)(l_l + ms * 16 + quad * 4);
    #pragma unroll
    for (int i = 0; i < 2; ++i) {
      int col = h * 128 + (w * 2 + i) * 16 + ln;
      #pragma unroll
      for (int r = 0; r < 4; ++r) {
        int row = m0 + ms * 16 + quad * 4 + r;
        Out[(size_t)row * 4096 + col] = oacc[ms][i][r] / lv[r];
      }
    }
  }
}

// ---------------------------------------------------------------------------
extern "C" void kernel_launch(void* const* d_in, const int* in_sizes, int n_in,
                              void* d_out, int out_size, void* d_ws, size_t ws_size,
                              hipStream_t stream) {
  const float* X  = (const float*)d_in[0];
  const float* Wq = (const float*)d_in[1];
  const float* Wk = (const float*)d_in[2];
  const float* Wv = (const float*)d_in[3];
  const float* cK = (const float*)d_in[4];
  const float* cV = (const float*)d_in[5];
  float* out = (float*)d_out;

  const size_t E  = (size_t)MM * NN;         // 4,194,304 elements
  const size_t WE = (size_t)NN * NN;         // 16,777,216 elements
  short* Xh  = (short*)d_ws;                 // bf16 [M][N]      8 MB
  short* Xl  = Xh + E;                       // bf16 [M][N]      8 MB
  short* Vb  = Xl + E;                       // bf16 [M][N]      8 MB
  float* Qf  = (float*)(Vb + E);             // f32  [M][N]     16 MB
  float* Kf  = Qf + E;                       // f32  [M][N]     16 MB
  short* Wth = (short*)(Kf + E);             // bf16 [N][N] T   32 MB (reused)
  short* Wtl = Wth + WE;                     // bf16 [N][N] T   32 MB (reused)

  {
    int n8 = (int)(E / 8);
    split_x<<<n8 / 256, 256, 0, stream>>>(X, Xh, Xl, n8);
  }

  dim3 gw(NN / 256, NN / 64);
  dim3 gg(NN / 128, MM / 128);

  // Q projection
  split_w_t<<<gw, 256, 0, stream>>>(Wq, Wth, Wtl);
  gemm_split_bt<<<gg, 256, 0, stream>>>(Xh, Xl, Wth, Wtl, Qf);

  // K projection (reuse transposed-weight buffers)
  split_w_t<<<gw, 256, 0, stream>>>(Wk, Wth, Wtl);
  gemm_split_bt<<<gg, 256, 0, stream>>>(Xh, Xl, Wth, Wtl, Kf);

  // V projection (hi only)
  split_w_t<<<gw, 256, 0, stream>>>(Wv, Wth, nullptr);
  gemm_bf16_bt<<<gg, 256, 0, stream>>>(Xh, Wth, Vb);

  dim3 gn(MM, 2);
  rmsnorm_f32<<<gn, 256, 0, stream>>>(Qf, Kf);

  dim3 ga(MM / 64, HH);
  attn<<<ga, 256, 0, stream>>>(Qf, Kf, Vb, cK, cV, out);
}

// Round 2
// 918.743 us; speedup vs baseline: 1.2232x; 1.1135x over previous
//
#include <hip/hip_runtime.h>

#define MM 1024
#define NN 4096
#define DD 128
#define HH 32
#define PP 3072
#define LL 4096   // P + M

typedef __attribute__((ext_vector_type(8))) short short8;
typedef __attribute__((ext_vector_type(4))) float f32x4;

__device__ __forceinline__ float bf2f(short b) {
  union { unsigned u; float f; } c;
  c.u = ((unsigned)(unsigned short)b) << 16;
  return c.f;
}

__device__ __forceinline__ short f2bf(float f) {
  union { float f; unsigned u; } c; c.f = f;
  unsigned r = c.u + 0x7FFFu + ((c.u >> 16) & 1u);  // RNE
  return (short)(r >> 16);
}

// split f32 -> bf16 hi + bf16 lo (x ~= hi + lo, residual ~2^-16 rel)
struct bf2 { short hi, lo; };
__device__ __forceinline__ bf2 split2(float x) {
  bf2 r;
  r.hi = f2bf(x);
  r.lo = f2bf(x - bf2f(r.hi));
  return r;
}

// 8 consecutive f32 -> 8 bf16 (plain cast)
__device__ __forceinline__ short8 cvt8(const float* __restrict__ p) {
  const f32x4 a = *(const f32x4*)p;
  const f32x4 b = *(const f32x4*)(p + 4);
  short8 r;
  r[0] = f2bf(a[0]); r[1] = f2bf(a[1]); r[2] = f2bf(a[2]); r[3] = f2bf(a[3]);
  r[4] = f2bf(b[0]); r[5] = f2bf(b[1]); r[6] = f2bf(b[2]); r[7] = f2bf(b[3]);
  return r;
}

// async global -> LDS, 16B per lane, LDS dest = wave-uniform base + lane*16
__device__ __forceinline__ void gload16(const void* g, void* l) {
  __builtin_amdgcn_global_load_lds(
      (const __attribute__((address_space(1))) void*)g,
      (__attribute__((address_space(3))) void*)l, 16, 0, 0);
}

// ---------------------------------------------------------------------------
// Split X f32 -> Xhi, Xlo bf16 (8 elems/thread).
// ---------------------------------------------------------------------------
__global__ __launch_bounds__(256) void split_x(
    const float* __restrict__ in, short* __restrict__ oh,
    short* __restrict__ ol, int n8)
{
  int i = blockIdx.x * blockDim.x + threadIdx.x;
  if (i >= n8) return;
  const float* p = in + (size_t)i * 8;
  f32x4 a = *(const f32x4*)p, b = *(const f32x4*)(p + 4);
  short8 h, l;
  #pragma unroll
  for (int j = 0; j < 4; ++j) {
    bf2 ra = split2(a[j]); h[j] = ra.hi; l[j] = ra.lo;
    bf2 rb = split2(b[j]); h[4 + j] = rb.hi; l[4 + j] = rb.lo;
  }
  *(short8*)(oh + (size_t)i * 8) = h;
  *(short8*)(ol + (size_t)i * 8) = l;
}

// ---------------------------------------------------------------------------
// Split + transpose W: f32 [K][N] -> bf16 hi/lo [N][K] (K-major).
// ---------------------------------------------------------------------------
__global__ __launch_bounds__(256) void split_w_t(
    const float* __restrict__ W, short* __restrict__ oh,
    short* __restrict__ ol)
{
  const int n0 = blockIdx.x * 256;
  const int k0 = blockIdx.y * 64;
  const int t  = threadIdx.x;
  const int k8 = k0 + ((t >> 5) << 3);   // 8-row k block
  const int n8 = n0 + ((t & 31) << 3);   // 8-col n block

  f32x4 xa[8], xb[8];
  #pragma unroll
  for (int r = 0; r < 8; ++r) {
    const float* p = W + (size_t)(k8 + r) * 4096 + n8;
    xa[r] = *(const f32x4*)p;
    xb[r] = *(const f32x4*)(p + 4);
  }
  #pragma unroll
  for (int c = 0; c < 8; ++c) {
    short8 th, tl;
    #pragma unroll
    for (int r = 0; r < 8; ++r) {
      float v = (c < 4) ? xa[r][c] : xb[r][c - 4];
      bf2 s = split2(v);
      th[r] = s.hi; tl[r] = s.lo;
    }
    size_t o = (size_t)(n8 + c) * 4096 + k8;
    *(short8*)(oh + o) = th;
    if (ol) *(short8*)(ol + o) = tl;
  }
}

// ---------------------------------------------------------------------------
// Split-precision bf16 GEMM, B^T layout (m97 structure):
//   O f32 [M][N] = Xh+Xl  @  (Wh+Wl)^T   (3 MFMA terms: hh, hl, lh)
// ---------------------------------------------------------------------------
__global__ __launch_bounds__(256) void gemm_split_bt(
    const short* __restrict__ Ah_g, const short* __restrict__ Al_g,
    const short* __restrict__ Bh_g, const short* __restrict__ Bl_g,
    float* __restrict__ O)
{
  const int n0 = blockIdx.x * 128;
  const int m0 = blockIdx.y * 128;
  const int t  = threadIdx.x;
  const int wave = t >> 6;
  const int lane = t & 63;
  const int ln   = lane & 15;
  const int quad = lane >> 4;
  const int q8   = quad * 8;
  const int wm = (wave >> 1) * 64;
  const int wn = (wave & 1) * 64;
  const int sr = lane >> 3;        // sub-row within 8-row staging chunk
  const int sc = (lane & 7) * 8;   // k offset within row

  __shared__ short Ash[128 * 64];
  __shared__ short Asl[128 * 64];
  __shared__ short Bsh[128 * 64];
  __shared__ short Bsl[128 * 64];

  f32x4 acc[4][4];
  #pragma unroll
  for (int mi = 0; mi < 4; ++mi)
    #pragma unroll
    for (int ni = 0; ni < 4; ++ni)
      acc[mi][ni] = (f32x4){0.f, 0.f, 0.f, 0.f};

  const size_t a_base = (size_t)(m0 + wave * 32 + sr) * 4096 + sc;
  const size_t b_base = (size_t)(n0 + wave * 32 + sr) * 4096 + sc;
  const int l_base = wave * 32 * 64;  // shorts

  for (int kt = 0; kt < 4096; kt += 64) {
    #pragma unroll
    for (int i = 0; i < 4; ++i) {
      size_t ao = a_base + kt + (size_t)(i * 8) * 4096;
      size_t bo = b_base + kt + (size_t)(i * 8) * 4096;
      int lo = l_base + i * 8 * 64;
      gload16(Ah_g + ao, Ash + lo);
      gload16(Al_g + ao, Asl + lo);
      gload16(Bh_g + bo, Bsh + lo);
      gload16(Bl_g + bo, Bsl + lo);
    }
    __syncthreads();
    #pragma unroll
    for (int kk = 0; kk < 64; kk += 32) {
      short8 ah[4], al[4], bh[4], bl[4];
      #pragma unroll
      for (int mi = 0; mi < 4; ++mi) {
        int ro = (wm + mi * 16 + ln) * 64 + kk + q8;
        ah[mi] = *(const short8*)(Ash + ro);
        al[mi] = *(const short8*)(Asl + ro);
      }
      #pragma unroll
      for (int ni = 0; ni < 4; ++ni) {
        int ro = (wn + ni * 16 + ln) * 64 + kk + q8;
        bh[ni] = *(const short8*)(Bsh + ro);
        bl[ni] = *(const short8*)(Bsl + ro);
      }
      #pragma unroll
      for (int ni = 0; ni < 4; ++ni)
        #pragma unroll
        for (int mi = 0; mi < 4; ++mi) {
          acc[mi][ni] = __builtin_amdgcn_mfma_f32_16x16x32_bf16(ah[mi], bh[ni], acc[mi][ni], 0, 0, 0);
          acc[mi][ni] = __builtin_amdgcn_mfma_f32_16x16x32_bf16(ah[mi], bl[ni], acc[mi][ni], 0, 0, 0);
          acc[mi][ni] = __builtin_amdgcn_mfma_f32_16x16x32_bf16(al[mi], bh[ni], acc[mi][ni], 0, 0, 0);
        }
    }
    __syncthreads();
  }

  #pragma unroll
  for (int mi = 0; mi < 4; ++mi)
    #pragma unroll
    for (int ni = 0; ni < 4; ++ni)
      #pragma unroll
      for (int r = 0; r < 4; ++r) {
        int row = m0 + wm + mi * 16 + quad * 4 + r;
        int col = n0 + wn + ni * 16 + ln;
        O[(size_t)row * 4096 + col] = acc[mi][ni][r];
      }
}

// ---------------------------------------------------------------------------
// Plain bf16 GEMM, B^T layout: Ov bf16 = Xh @ Wth^T.
// ---------------------------------------------------------------------------
__global__ __launch_bounds__(256) void gemm_bf16_bt(
    const short* __restrict__ Ah_g, const short* __restrict__ Bh_g,
    short* __restrict__ Ov)
{
  const int n0 = blockIdx.x * 128;
  const int m0 = blockIdx.y * 128;
  const int t  = threadIdx.x;
  const int wave = t >> 6;
  const int lane = t & 63;
  const int ln   = lane & 15;
  const int quad = lane >> 4;
  const int q8   = quad * 8;
  const int wm = (wave >> 1) * 64;
  const int wn = (wave & 1) * 64;
  const int sr = lane >> 3;
  const int sc = (lane & 7) * 8;

  __shared__ short Ash[128 * 64];
  __shared__ short Bsh[128 * 64];

  f32x4 acc[4][4];
  #pragma unroll
  for (int mi = 0; mi < 4; ++mi)
    #pragma unroll
    for (int ni = 0; ni < 4; ++ni)
      acc[mi][ni] = (f32x4){0.f, 0.f, 0.f, 0.f};

  const size_t a_base = (size_t)(m0 + wave * 32 + sr) * 4096 + sc;
  const size_t b_base = (size_t)(n0 + wave * 32 + sr) * 4096 + sc;
  const int l_base = wave * 32 * 64;

  for (int kt = 0; kt < 4096; kt += 64) {
    #pragma unroll
    for (int i = 0; i < 4; ++i) {
      size_t ao = a_base + kt + (size_t)(i * 8) * 4096;
      size_t bo = b_base + kt + (size_t)(i * 8) * 4096;
      int lo = l_base + i * 8 * 64;
      gload16(Ah_g + ao, Ash + lo);
      gload16(Bh_g + bo, Bsh + lo);
    }
    __syncthreads();
    #pragma unroll
    for (int kk = 0; kk < 64; kk += 32) {
      short8 ah[4], bh[4];
      #pragma unroll
      for (int mi = 0; mi < 4; ++mi)
        ah[mi] = *(const short8*)(Ash + (wm + mi * 16 + ln) * 64 + kk + q8);
      #pragma unroll
      for (int ni = 0; ni < 4; ++ni)
        bh[ni] = *(const short8*)(Bsh + (wn + ni * 16 + ln) * 64 + kk + q8);
      #pragma unroll
      for (int ni = 0; ni < 4; ++ni)
        #pragma unroll
        for (int mi = 0; mi < 4; ++mi)
          acc[mi][ni] = __builtin_amdgcn_mfma_f32_16x16x32_bf16(ah[mi], bh[ni], acc[mi][ni], 0, 0, 0);
    }
    __syncthreads();
  }

  #pragma unroll
  for (int mi = 0; mi < 4; ++mi)
    #pragma unroll
    for (int ni = 0; ni < 4; ++ni)
      #pragma unroll
      for (int r = 0; r < 4; ++r) {
        int row = m0 + wm + mi * 16 + quad * 4 + r;
        int col = n0 + wn + ni * 16 + ln;
        Ov[(size_t)row * 4096 + col] = f2bf(acc[mi][ni][r]);
      }
}

// ---------------------------------------------------------------------------
// RMS-norm f32 in place per (row, head): 8 lanes/head, 16 f32/lane.
// grid (1024, 2): y==0 -> Q, y==1 -> K.
// ---------------------------------------------------------------------------
__global__ __launch_bounds__(256) void rmsnorm_f32(
    float* __restrict__ Q, float* __restrict__ K)
{
  float* __restrict__ buf = (blockIdx.y == 0) ? Q : K;
  const int m = blockIdx.x;
  const int t = threadIdx.x;
  const int head = t >> 3, li = t & 7;
  size_t base = (size_t)m * 4096 + head * 128 + li * 16;

  f32x4 a[4];
  float ss = 0.f;
  #pragma unroll
  for (int i = 0; i < 4; ++i) {
    a[i] = *(const f32x4*)(buf + base + i * 4);
    #pragma unroll
    for (int j = 0; j < 4; ++j) ss += a[i][j] * a[i][j];
  }
  #pragma unroll
  for (int d = 1; d < 8; d <<= 1) ss += __shfl_xor(ss, d, 64);
  float scale = rsqrtf(ss * (1.0f / 128.0f));
  #pragma unroll
  for (int i = 0; i < 4; ++i) {
    #pragma unroll
    for (int j = 0; j < 4; ++j) a[i][j] *= scale;
    *(f32x4*)(buf + base + i * 4) = a[i];
  }
}

// ---------------------------------------------------------------------------
// prep_k: cK (f32) + Kf (f32, rms-normed) -> Khi/Klo bf16 [H][4096][128],
// 16B-block XOR swizzle baked in: logical d-block b stored at b ^ (key&7).
// grid (64 tiles, 32 heads), 256 thr. Tiles 0..47 = cache, 48..63 = new.
// ---------------------------------------------------------------------------
__global__ __launch_bounds__(256) void prep_k(
    const float* __restrict__ Kf, const float* __restrict__ cK,
    short* __restrict__ Khi, short* __restrict__ Klo)
{
  const int h  = blockIdx.y;
  const int k0 = blockIdx.x * 64;
  const int t  = threadIdx.x;
  const int d0 = (t & 7) * 16;   // 16 f32 per thread per row
  #pragma unroll
  for (int i = 0; i < 2; ++i) {
    int key = k0 + i * 32 + (t >> 3);
    const float* src = (key < PP)
        ? cK + ((size_t)h * PP + key) * 128 + d0
        : Kf + (size_t)(key - PP) * 4096 + h * 128 + d0;
    f32x4 x0 = *(const f32x4*)src,       x1 = *(const f32x4*)(src + 4);
    f32x4 x2 = *(const f32x4*)(src + 8), x3 = *(const f32x4*)(src + 12);
    short8 h0, l0, h1, l1;
    #pragma unroll
    for (int j = 0; j < 4; ++j) {
      bf2 r0 = split2(x0[j]); h0[j] = r0.hi; l0[j] = r0.lo;
      bf2 r1 = split2(x1[j]); h0[4 + j] = r1.hi; l0[4 + j] = r1.lo;
      bf2 r2 = split2(x2[j]); h1[j] = r2.hi; l1[j] = r2.lo;
      bf2 r3 = split2(x3[j]); h1[4 + j] = r3.hi; l1[4 + j] = r3.lo;
    }
    size_t row = ((size_t)h * 4096 + key) * 128;
    int s  = key & 7;
    int b0 = (t & 7) * 2, b1 = b0 + 1;
    *(short8*)(Khi + row + ((b0 ^ s) << 3)) = h0;
    *(short8*)(Khi + row + ((b1 ^ s) << 3)) = h1;
    *(short8*)(Klo + row + ((b0 ^ s) << 3)) = l0;
    *(short8*)(Klo + row + ((b1 ^ s) << 3)) = l1;
  }
}

// ---------------------------------------------------------------------------
// prep_v: cV (f32) + Vb (bf16) -> Vtt bf16, pre-transposed + pre-tiled:
// [H][tile=L/64][d=128][key=64], swizzled (key-block kb stored at kb^(d&7)),
// so each tile is the exact 16 KB LDS image for attn's PV B-operand.
// grid (32 x-blocks of 128 keys, 32 heads), 256 thr, 8x8 reg transpose.
// ---------------------------------------------------------------------------
__global__ __launch_bounds__(256) void prep_v(
    const short* __restrict__ Vb, const float* __restrict__ cV,
    short* __restrict__ Vtt)
{
  const int h    = blockIdx.y;
  const int k0   = blockIdx.x * 128;
  const int t    = threadIdx.x;
  const int kb_g = (k0 >> 3) + (t >> 4);  // global key-8-block
  const int db   = t & 15;                // d-8-block
  const int key0 = kb_g * 8;

  short8 row[8];
  if (key0 < PP) {
    #pragma unroll
    for (int r = 0; r < 8; ++r)
      row[r] = cvt8(cV + ((size_t)h * PP + key0 + r) * 128 + db * 8);
  } else {
    #pragma unroll
    for (int r = 0; r < 8; ++r)
      row[r] = *(const short8*)(Vb + (size_t)(key0 + r - PP) * 4096 + h * 128 + db * 8);
  }

  const int tile = kb_g >> 3, kbt = kb_g & 7;
  size_t tb = ((size_t)h * 64 + tile) * 8192;
  #pragma unroll
  for (int c = 0; c < 8; ++c) {
    int d = db * 8 + c;                  // d & 7 == c
    short8 o;
    #pragma unroll
    for (int r = 0; r < 8; ++r) o[r] = row[r][c];
    *(short8*)(Vtt + tb + d * 64 + ((kbt ^ c) << 3)) = o;
  }
}

// ---------------------------------------------------------------------------
// Flash attention, 64 q-rows/block, 4 waves. All operands pre-split/
// pre-transposed bf16 in global, staged via global_load_lds (no staging
// VALU). K LDS [64][128] swizzled; V^T LDS [128][64] swizzled; both read
// with contiguous ds_read_b128.
// ---------------------------------------------------------------------------
__global__ __launch_bounds__(256) void attn(
    const float* __restrict__ Qf,   // [M][4096] f32 rms-normed q
    const short* __restrict__ Khi,  // [H][L][128] bf16 swizzled
    const short* __restrict__ Klo,
    const short* __restrict__ Vtt,  // [H][L/64][128][64] bf16 swizzled
    float* __restrict__ Out)        // [M][4096] f32
{
  const int h  = blockIdx.y;
  const int m0 = blockIdx.x * 64;
  const int t  = threadIdx.x;
  const int w    = t >> 6;
  const int lane = t & 63;
  const int ln   = lane & 15;
  const int quad = lane >> 4;
  const int q8   = quad * 8;

  __shared__ short k_hi[64 * 128];
  __shared__ short k_lo[64 * 128];
  __shared__ short v_t[128 * 64];
  __shared__ short p_s[64 * 72];
  __shared__ float a_l[64], l_l[64];

  // q fragments from global, split in registers (A layout: m=ln, k=q8+j)
  short8 qh[4], ql[4];
  {
    int qrow = m0 + w * 16 + ln;
    #pragma unroll
    for (int dc = 0; dc < 4; ++dc) {
      const float* qp = Qf + (size_t)qrow * 4096 + h * 128 + dc * 32 + q8;
      f32x4 a = *(const f32x4*)qp, b = *(const f32x4*)(qp + 4);
      #pragma unroll
      for (int j = 0; j < 4; ++j) {
        bf2 ra = split2(a[j]); qh[dc][j] = ra.hi; ql[dc][j] = ra.lo;
        bf2 rb = split2(b[j]); qh[dc][4 + j] = rb.hi; ql[dc][4 + j] = rb.lo;
      }
    }
  }

  float m_st[4], l_st[4];
  #pragma unroll
  for (int r = 0; r < 4; ++r) { m_st[r] = -1e30f; l_st[r] = 0.f; }

  f32x4 oacc[4][2];
  #pragma unroll
  for (int ms = 0; ms < 4; ++ms)
    #pragma unroll
    for (int i = 0; i < 2; ++i)
      oacc[ms][i] = (f32x4){0.f, 0.f, 0.f, 0.f};

  const size_t khead = (size_t)h * 4096 * 128;
  const size_t vhead = (size_t)h * 64 * 8192;

  for (int kb = 0; kb < LL; kb += 64) {
    // ---- stage K hi/lo and V^T tiles: pure byte copies, swizzle pre-baked
    const size_t kt = khead + (size_t)kb * 128;
    const size_t vt = vhead + (size_t)(kb >> 6) * 8192;
    #pragma unroll
    for (int i = 0; i < 4; ++i) {
      int lo = i * 2048 + w * 512;   // wave-uniform LDS base (shorts)
      gload16(Khi + kt + lo + lane * 8, k_hi + lo);
      gload16(Klo + kt + lo + lane * 8, k_lo + lo);
      gload16(Vtt + vt + lo + lane * 8, v_t + lo);
    }
    __syncthreads();

    // ---- S = q K^T (wave's 16 rows x 64 keys), 3-term split
    f32x4 sacc[4];
    #pragma unroll
    for (int ni = 0; ni < 4; ++ni) sacc[ni] = (f32x4){0.f, 0.f, 0.f, 0.f};
    __builtin_amdgcn_s_setprio(1);
    #pragma unroll
    for (int ni = 0; ni < 4; ++ni) {
      const int r = ni * 16 + ln;
      #pragma unroll
      for (int dc = 0; dc < 4; ++dc) {
        int ro = r * 128 + (((dc * 4 + quad) ^ (r & 7)) << 3);
        short8 kh = *(const short8*)(k_hi + ro);
        short8 kl = *(const short8*)(k_lo + ro);
        sacc[ni] = __builtin_amdgcn_mfma_f32_16x16x32_bf16(qh[dc], kh, sacc[ni], 0, 0, 0);
        sacc[ni] = __builtin_amdgcn_mfma_f32_16x16x32_bf16(qh[dc], kl, sacc[ni], 0, 0, 0);
        sacc[ni] = __builtin_amdgcn_mfma_f32_16x16x32_bf16(ql[dc], kh, sacc[ni], 0, 0, 0);
      }
    }
    __builtin_amdgcn_s_setprio(0);

    // ---- wave-private online softmax (rows quad*4+rr of this wave)
    float alpha[4];
    #pragma unroll
    for (int rr = 0; rr < 4; ++rr) {
      float mx = fmaxf(fmaxf(sacc[0][rr], sacc[1][rr]),
                       fmaxf(sacc[2][rr], sacc[3][rr]));
      #pragma unroll
      for (int d = 1; d < 16; d <<= 1) mx = fmaxf(mx, __shfl_xor(mx, d, 64));
      float mn = fmaxf(m_st[rr], mx);
      alpha[rr] = __expf(m_st[rr] - mn);
      float p0 = __expf(sacc[0][rr] - mn);
      float p1 = __expf(sacc[1][rr] - mn);
      float p2 = __expf(sacc[2][rr] - mn);
      float p3 = __expf(sacc[3][rr] - mn);
      float s = p0 + p1 + p2 + p3;
      #pragma unroll
      for (int d = 1; d < 16; d <<= 1) s += __shfl_xor(s, d, 64);
      l_st[rr] = l_st[rr] * alpha[rr] + s;
      m_st[rr] = mn;
      int prow = (w * 16 + quad * 4 + rr) * 72;
      p_s[prow + 0 * 16 + ln] = f2bf(p0);
      p_s[prow + 1 * 16 + ln] = f2bf(p1);
      p_s[prow + 2 * 16 + ln] = f2bf(p2);
      p_s[prow + 3 * 16 + ln] = f2bf(p3);
    }
    if (ln == 0) {
      #pragma unroll
      for (int rr = 0; rr < 4; ++rr) a_l[w * 16 + quad * 4 + rr] = alpha[rr];
    }
    __syncthreads();

    // ---- rescale O, then O += P V (wave owns d-subtiles 2w, 2w+1)
    #pragma unroll
    for (int ms = 0; ms < 4; ++ms) {
      f32x4 av = *(const f32x4*)(a_l + ms * 16 + quad * 4);
      #pragma unroll
      for (int i = 0; i < 2; ++i)
        #pragma unroll
        for (int r = 0; r < 4; ++r) oacc[ms][i][r] *= av[r];
    }
    #pragma unroll
    for (int kk = 0; kk < 64; kk += 32) {
      short8 vf[2];
      #pragma unroll
      for (int i = 0; i < 2; ++i) {
        int d = (w * 2 + i) * 16 + ln;
        int ro = d * 64 + ((((kk + q8) >> 3) ^ (d & 7)) << 3);
        vf[i] = *(const short8*)(v_t + ro);
      }
      __builtin_amdgcn_s_setprio(1);
      #pragma unroll
      for (int ms = 0; ms < 4; ++ms) {
        short8 pf = *(const short8*)(p_s + (ms * 16 + ln) * 72 + kk + q8);
        #pragma unroll
        for (int i = 0; i < 2; ++i)
          oacc[ms][i] = __builtin_amdgcn_mfma_f32_16x16x32_bf16(pf, vf[i], oacc[ms][i], 0, 0, 0);
      }
      __builtin_amdgcn_s_setprio(0);
    }
    __syncthreads();
  }

  if (ln == 0) {
    #pragma unroll
    for (int rr = 0; rr < 4; ++rr) l_l[w * 16 + quad * 4 + rr] = l_st[rr];
  }
  __syncthreads();

  #pragma unroll
  for (int ms = 0; ms < 4; ++ms) {
    f32x4 lv = *(const f32x4*)(l_l + ms * 16 + quad * 4);
    #pragma unroll
    for (int i = 0; i < 2; ++i) {
      int col = h * 128 + (w * 2 + i) * 16 + ln;
      #pragma unroll
      for (int r = 0; r < 4; ++r) {
        int row = m0 + ms * 16 + quad * 4 + r;
        Out[(size_t)row * 4096 + col] = oacc[ms][i][r] / lv[r];
      }
    }
  }
}

// ---------------------------------------------------------------------------
extern "C" void kernel_launch(void* const* d_in, const int* in_sizes, int n_in,
                              void* d_out, int out_size, void* d_ws, size_t ws_size,
                              hipStream_t stream) {
  const float* X  = (const float*)d_in[0];
  const float* Wq = (const float*)d_in[1];
  const float* Wk = (const float*)d_in[2];
  const float* Wv = (const float*)d_in[3];
  const float* cK = (const float*)d_in[4];
  const float* cV = (const float*)d_in[5];
  float* out = (float*)d_out;

  const size_t MB = 1u << 20;
  char* w = (char*)d_ws;
  // Phase-1 layout (projections):
  float* Qf  = (float*)(w);             // 16 MB [0,16)
  float* Kf  = (float*)(w + 16 * MB);   // 16 MB [16,32)
  short* Xh  = (short*)(w + 32 * MB);   //  8 MB [32,40)
  short* Xl  = (short*)(w + 40 * MB);   //  8 MB [40,48)
  short* Vb  = (short*)(w + 48 * MB);   //  8 MB [48,56)
  short* Wth = (short*)(w + 56 * MB);   // 32 MB [56,88)
  short* Wtl = (short*)(w + 88 * MB);   // 32 MB [88,120)
  // Phase-2 overlays (after producers are done on the same stream):
  short* Khi = (short*)(w + 56 * MB);   // 32 MB over Wth (dead after gemms)
  short* Klo = (short*)(w + 88 * MB);   // 32 MB over Wtl (dead after gemms)
  short* Vtt = (short*)(w + 16 * MB);   // 32 MB over Kf/Xh/Xl (dead after prep_k)

  {
    int n8 = (int)((size_t)MM * NN / 8);
    split_x<<<n8 / 256, 256, 0, stream>>>(X, Xh, Xl, n8);
  }

  dim3 gw(NN / 256, NN / 64);
  dim3 gg(NN / 128, MM / 128);

  // Q projection
  split_w_t<<<gw, 256, 0, stream>>>(Wq, Wth, Wtl);
  gemm_split_bt<<<gg, 256, 0, stream>>>(Xh, Xl, Wth, Wtl, Qf);

  // K projection (reuse transposed-weight buffers)
  split_w_t<<<gw, 256, 0, stream>>>(Wk, Wth, Wtl);
  gemm_split_bt<<<gg, 256, 0, stream>>>(Xh, Xl, Wth, Wtl, Kf);

  // V projection (hi only)
  split_w_t<<<gw, 256, 0, stream>>>(Wv, Wth, nullptr);
  gemm_bf16_bt<<<gg, 256, 0, stream>>>(Xh, Wth, Vb);

  dim3 gn(MM, 2);
  rmsnorm_f32<<<gn, 256, 0, stream>>>(Qf, Kf);

  // K/V pre-split/transpose for attention (order matters: prep_k reads Kf,
  // prep_v's output overlays Kf).
  dim3 gk(LL / 64, HH);
  prep_k<<<gk, 256, 0, stream>>>(Kf, cK, Khi, Klo);
  dim3 gv(LL / 128, HH);
  prep_v<<<gv, 256, 0, stream>>>(Vb, cV, Vtt);

  dim3 ga(MM / 64, HH);
  attn<<<ga, 256, 0, stream>>>(Qf, Khi, Klo, Vtt, out);
}